// Round 8
// baseline (702.339 us; speedup 1.0000x reference)
//
#include <hip/hip_runtime.h>
#include <stdint.h>

typedef unsigned short u16;
typedef unsigned short u16x4 __attribute__((ext_vector_type(4)));
typedef short bf16x8 __attribute__((ext_vector_type(8)));
typedef float f32x4 __attribute__((ext_vector_type(4)));

#define CDIM 256
#define MSZ 65536

// ---------------- ws layout (bytes) ----------------
constexpr size_t O_XB   = 0;                       // 64MB x bf16 NHWC
constexpr size_t O_AT   = 67108864;                // fp32 A^T (dead after scale)
constexpr size_t O_PQH  = 67108864;                // alias AT
constexpr size_t O_PQL  = O_PQH + 524288;
constexpr size_t O_SVAL = 68419584;
constexpr size_t O_W0   = 68419840;                // h,l,th,tl each 655360 B
constexpr size_t O_W1   = 71041280;
constexpr size_t O_PH   = 71041280;                // alias W1 (dead after bjorck)
constexpr size_t O_PL   = O_PH + 524288;
constexpr size_t O_QTH  = O_PL + 524288;
constexpr size_t O_QTL  = O_QTH + 524288;
constexpr size_t O_TH   = 73662720;
constexpr size_t O_TL   = O_TH + 655360;
constexpr size_t O_C1H  = 73662720;                // alias T (dead after bjorck)
constexpr size_t O_C1L  = O_C1H + 131072;
constexpr size_t O_C2H  = O_C1L + 131072;
constexpr size_t O_C2L  = O_C2H + 131072;
constexpr size_t O_C2TH = O_C2L + 131072;
constexpr size_t O_C2TL = O_C2TH + 131072;
constexpr size_t O_RTH  = 74973440;
constexpr size_t O_RTL  = O_RTH + 1179648;
constexpr size_t O_WBQ  = O_RTL + 1179648;

__device__ __forceinline__ u16 f2bf(float f) {
  union { float f; uint32_t u; } a; a.f = f;
  uint32_t u = a.u;
  uint32_t r = u + 0x7FFFu + ((u >> 16) & 1u);
  return (u16)(r >> 16);
}
__device__ __forceinline__ float bf2f(u16 u) {
  union { uint32_t u; float f; } a; a.u = ((uint32_t)u) << 16; return a.f;
}
__device__ __forceinline__ void split_st(u16* hi, u16* lo, float v) {
  u16 h = f2bf(v);
  *hi = h;
  *lo = f2bf(v - bf2f(h));
}

// ---------------- x: NCHW f32 -> NHWC bf16 (vectorized store) ----------------
__global__ void convert_k(const float* __restrict__ x, u16* __restrict__ xb) {
  __shared__ float t[32][33];
  int b = blockIdx.x;
  int ctile = b & 7, wtile = (b >> 3) & 1, h = (b >> 4) & 63, n = b >> 10;
  int c0 = ctile * 32, w0 = wtile * 32;
  int tid = threadIdx.x;
  for (int p = 0; p < 4; p++) {
    int e = tid + p * 256; int cc = e >> 5, ww = e & 31;
    t[cc][ww] = x[(((size_t)n * 256 + c0 + cc) * 64 + h) * 64 + w0 + ww];
  }
  __syncthreads();
  {
    int ww = tid >> 3, c4 = (tid & 7) * 4;
    u16x4 v;
    #pragma unroll
    for (int j = 0; j < 4; ++j) v[j] = f2bf(t[c4 + j][ww]);
    *(u16x4*)&xb[(((size_t)n * 64 + h) * 64 + w0 + ww) * 256 + c0 + c4] = v;
  }
}

// ---------------- At = A^T (fp32, for power iteration) ----------------
__global__ void transpose_k(const float* __restrict__ A, float* __restrict__ At) {
  __shared__ float t[32][33];
  int m = blockIdx.y;
  int i0 = (blockIdx.x >> 3) * 32, j0 = (blockIdx.x & 7) * 32;
  int tid = threadIdx.x;
  const float* Am = A + (size_t)m * MSZ;
  float* Atm = At + (size_t)m * MSZ;
  for (int p = 0; p < 4; p++) {
    int e = tid + p * 256; int ii = e >> 5, jj = e & 31;
    t[ii][jj] = Am[(i0 + ii) * CDIM + j0 + jj];
  }
  __syncthreads();
  for (int p = 0; p < 4; p++) {
    int e = tid + p * 256; int jj = e >> 5, ii = e & 31;
    Atm[(j0 + jj) * CDIM + i0 + ii] = t[ii][jj];
  }
}

// ---------------- power iteration: sval[m] = sigma_max ----------------
__global__ void power_k(const float* __restrict__ A, const float* __restrict__ At,
                        const float* __restrict__ u0, float* __restrict__ sval) {
  int m = blockIdx.x; int t = threadIdx.x;
  __shared__ float u[CDIM], v[CDIM], red[4];
  const float* Am = A + (size_t)m * MSZ;
  const float* Atm = At + (size_t)m * MSZ;
  u[t] = u0[m * CDIM + t];
  __syncthreads();
  float nu = 1.0f;
  for (int it = 0; it < 10; ++it) {
    float a1 = 0.f;
    #pragma unroll 4
    for (int i = 0; i < CDIM; i++) a1 += Am[i * CDIM + t] * u[i];
    float ss = a1 * a1;
    for (int off = 32; off; off >>= 1) ss += __shfl_down(ss, off);
    __syncthreads();
    if ((t & 63) == 0) red[t >> 6] = ss;
    __syncthreads();
    float nv = sqrtf(red[0] + red[1] + red[2] + red[3]);
    v[t] = a1 / nv;
    __syncthreads();
    float a2 = 0.f;
    #pragma unroll 4
    for (int j = 0; j < CDIM; j++) a2 += Atm[j * CDIM + t] * v[j];
    float s2 = a2 * a2;
    for (int off = 32; off; off >>= 1) s2 += __shfl_down(s2, off);
    __syncthreads();
    if ((t & 63) == 0) red[t >> 6] = s2;
    __syncthreads();
    nu = sqrtf(red[0] + red[1] + red[2] + red[3]);
    u[t] = a2 / nu;
    __syncthreads();
  }
  if (t == 0) sval[m] = nu;   // sigma = u^T A v = ||Av|| = last norm
}

// ---------------- scale + hi/lo split (W and W^T) ----------------
__global__ void scale_k(const float* __restrict__ param, const float* __restrict__ At,
                        const float* __restrict__ sval,
                        u16* __restrict__ Wh, u16* __restrict__ Wl,
                        u16* __restrict__ Wth, u16* __restrict__ Wtl) {
  size_t idx = (size_t)blockIdx.x * 256 + threadIdx.x;   // 1280 blocks -> 327680
  int m = (int)(idx >> 16);
  float inv = 1.0f / sval[m];
  float v = param[idx] * inv;
  split_st(&Wh[idx], &Wl[idx], v);
  float vt = At[idx] * inv;
  split_st(&Wth[idx], &Wtl[idx], vt);
}

// ---------------- hi/lo-split MFMA 32x32-tile GEMM: C += A·B^T ----------------
__device__ __forceinline__ void gemm32_acc(
    const u16* __restrict__ Ah, const u16* __restrict__ Al, int i0,
    const u16* __restrict__ Bh, const u16* __restrict__ Bl, int j0,
    int K, f32x4* acc, char* smem, int tid)
{
  int lane = tid & 63, wave = tid >> 6;
  int qm = wave >> 1, qn = wave & 1;
  int ra = qm * 16 + (lane & 15);
  int rb = qn * 16 + (lane & 15);
  int kb = (lane >> 4) * 16;
  for (int kc = 0; kc < K; kc += 128) {
    __syncthreads();
    #pragma unroll
    for (int p = 0; p < 8; ++p) {
      int e = tid + p * 256;
      int bufi = e >> 9;                 // 0:Ah 1:Al 2:Bh 3:Bl
      int r = (e >> 4) & 31;
      int cb = (e & 15) * 16;
      const u16* srcm = (bufi == 0) ? Ah : (bufi == 1) ? Al : (bufi == 2) ? Bh : Bl;
      int r0 = (bufi < 2) ? i0 : j0;
      const char* src = (const char*)srcm + ((size_t)(r0 + r) * 256 + kc) * 2 + cb;
      *(uint4*)(smem + bufi * 8192 + r * 256 + (cb ^ ((r & 7) << 4))) = *(const uint4*)src;
    }
    __syncthreads();
    #pragma unroll
    for (int ks = 0; ks < 4; ++ks) {
      int kbyte = ks * 64 + kb;
      int oa = ra * 256 + (kbyte ^ ((ra & 7) << 4));
      int ob = rb * 256 + (kbyte ^ ((rb & 7) << 4));
      bf16x8 ah = *(const bf16x8*)(smem + oa);
      bf16x8 al = *(const bf16x8*)(smem + 8192 + oa);
      bf16x8 bh = *(const bf16x8*)(smem + 16384 + ob);
      bf16x8 bl = *(const bf16x8*)(smem + 24576 + ob);
      *acc = __builtin_amdgcn_mfma_f32_16x16x32_bf16(ah, bh, *acc, 0, 0, 0);
      *acc = __builtin_amdgcn_mfma_f32_16x16x32_bf16(ah, bl, *acc, 0, 0, 0);
      *acc = __builtin_amdgcn_mfma_f32_16x16x32_bf16(al, bh, *acc, 0, 0, 0);
    }
  }
}

#define GEMM_IDX \
  int tid = threadIdx.x; \
  int lane = tid & 63, wave = tid >> 6, qm = wave >> 1, qn = wave & 1; \
  int orow = qm * 16 + ((lane >> 4) << 2); \
  int ocol = qn * 16 + (lane & 15); \
  int i0 = (blockIdx.x >> 3) * 32, j0 = (blockIdx.x & 7) * 32; \
  __shared__ char smem[32768];

// ---------------- Bjorck step 1: T = W^T W ----------------
__global__ __launch_bounds__(256) void bjorck_t_k(
    const u16* __restrict__ Wth, const u16* __restrict__ Wtl,
    u16* __restrict__ Th, u16* __restrict__ Tl) {
  GEMM_IDX
  size_t mo = (size_t)blockIdx.y * MSZ;
  f32x4 acc = {};
  gemm32_acc(Wth + mo, Wtl + mo, i0, Wth + mo, Wtl + mo, j0, 256, &acc, smem, tid);
  #pragma unroll
  for (int v = 0; v < 4; ++v) {
    size_t idx = mo + (size_t)(i0 + orow + v) * 256 + (j0 + ocol);
    split_st(&Th[idx], &Tl[idx], acc[v]);
  }
}

// ---------------- Bjorck step 2: Wn = 1.5W - 0.5 W·T (+ Wn^T) ----------------
__global__ __launch_bounds__(256) void bjorck_u_k(
    const u16* __restrict__ Wh, const u16* __restrict__ Wl,
    const u16* __restrict__ Th, const u16* __restrict__ Tl,
    u16* __restrict__ nWh, u16* __restrict__ nWl,
    u16* __restrict__ nWth, u16* __restrict__ nWtl) {
  GEMM_IDX
  size_t mo = (size_t)blockIdx.y * MSZ;
  f32x4 acc = {};
  gemm32_acc(Wh + mo, Wl + mo, i0, Th + mo, Tl + mo, j0, 256, &acc, smem, tid);
  #pragma unroll
  for (int v = 0; v < 4; ++v) {
    int r = i0 + orow + v, c = j0 + ocol;
    size_t idx = mo + (size_t)r * 256 + c;
    float wv = bf2f(Wh[idx]) + bf2f(Wl[idx]);
    float nv = 1.5f * wv - 0.5f * acc[v];
    split_st(&nWh[idx], &nWl[idx], nv);
    size_t idxT = mo + (size_t)c * 256 + r;
    split_st(&nWth[idxT], &nWtl[idxT], nv);
  }
}

// ---------------- PQ[t] = masked(O)·masked(O)^T (K=128) ----------------
__global__ __launch_bounds__(256) void pq_k(
    const u16* __restrict__ Wh, const u16* __restrict__ Wl,
    u16* __restrict__ PQh, u16* __restrict__ PQl) {
  GEMM_IDX
  int m4 = blockIdx.y;
  const u16* Oh = Wh + (size_t)(1 + m4) * MSZ;
  const u16* Ol = Wl + (size_t)(1 + m4) * MSZ;
  f32x4 acc = {};
  gemm32_acc(Oh, Ol, i0, Oh, Ol, j0, 128, &acc, smem, tid);
  #pragma unroll
  for (int v = 0; v < 4; ++v) {
    size_t idx = (size_t)m4 * MSZ + (size_t)(i0 + orow + v) * 256 + (j0 + ocol);
    split_st(&PQh[idx], &PQl[idx], acc[v]);
  }
}

// ---------------- C1 = PQ0·PQ1, C2 = PQ2·PQ3, C2t = PQ3·PQ2 ----------------
__global__ __launch_bounds__(256) void c12_k(
    const u16* __restrict__ PQh, const u16* __restrict__ PQl,
    u16* __restrict__ C1h, u16* __restrict__ C1l,
    u16* __restrict__ C2h, u16* __restrict__ C2l,
    u16* __restrict__ C2th, u16* __restrict__ C2tl) {
  GEMM_IDX
  int z = blockIdx.y;
  int ai = (z == 0) ? 0 : (z == 1) ? 2 : 3;
  int bi = (z == 0) ? 1 : (z == 1) ? 3 : 2;
  u16* oh = (z == 0) ? C1h : (z == 1) ? C2h : C2th;
  u16* ol = (z == 0) ? C1l : (z == 1) ? C2l : C2tl;
  f32x4 acc = {};
  gemm32_acc(PQh + (size_t)ai * MSZ, PQl + (size_t)ai * MSZ, i0,
             PQh + (size_t)bi * MSZ, PQl + (size_t)bi * MSZ, j0, 256, &acc, smem, tid);
  #pragma unroll
  for (int v = 0; v < 4; ++v) {
    size_t idx = (size_t)(i0 + orow + v) * 256 + (j0 + ocol);
    split_st(&oh[idx], &ol[idx], acc[v]);
  }
}

// ---------------- block-orth members: P[0..3], Q^T[0..3] (elementwise) ----------------
__global__ void blocks_k(const u16* __restrict__ PQh, const u16* __restrict__ PQl,
                         const u16* __restrict__ C1h, const u16* __restrict__ C1l,
                         const u16* __restrict__ C2th, const u16* __restrict__ C2tl,
                         u16* __restrict__ Ph, u16* __restrict__ Pl,
                         u16* __restrict__ QTh, u16* __restrict__ QTl) {
  size_t g = (size_t)blockIdx.x * 256 + threadIdx.x;   // 256 blocks -> 65536
  int row = (int)(g >> 8), col = (int)(g & 255);
  float I = (row == col) ? 1.f : 0.f;
  float p0 = bf2f(PQh[g]) + bf2f(PQl[g]);
  float p1 = bf2f(PQh[MSZ + g]) + bf2f(PQl[MSZ + g]);
  float c1 = bf2f(C1h[g]) + bf2f(C1l[g]);
  split_st(&Ph[g],           &Pl[g],           c1);
  split_st(&Ph[MSZ + g],     &Pl[MSZ + g],     p0 - c1);
  split_st(&Ph[2*MSZ + g],   &Pl[2*MSZ + g],   p1 - c1);
  split_st(&Ph[3*MSZ + g],   &Pl[3*MSZ + g],   I - p0 - p1 + c1);
  float q0 = bf2f(PQh[2*MSZ + g]) + bf2f(PQl[2*MSZ + g]);
  float q1 = bf2f(PQh[3*MSZ + g]) + bf2f(PQl[3*MSZ + g]);
  float c2t = bf2f(C2th[g]) + bf2f(C2tl[g]);
  split_st(&QTh[g],          &QTl[g],          c2t);
  split_st(&QTh[MSZ + g],    &QTl[MSZ + g],    q0 - c2t);
  split_st(&QTh[2*MSZ + g],  &QTl[2*MSZ + g],  q1 - c2t);
  split_st(&QTh[3*MSZ + g],  &QTl[3*MSZ + g],  I - q0 - q1 + c2t);
}

// ---------------- matrix_conv: R[ij] = sum_t P[tp]·Q[tq]; store R^T ----------------
__global__ __launch_bounds__(256) void mconv_k(
    const u16* __restrict__ Ph, const u16* __restrict__ Pl,
    const u16* __restrict__ QTh, const u16* __restrict__ QTl,
    u16* __restrict__ RTh, u16* __restrict__ RTl) {
  GEMM_IDX
  int ij = blockIdx.y;
  const int toff[10] = {0, 1, 3, 4, 6, 10, 12, 13, 15, 16};
  const int tp[16] = {0, 0, 1, 1, 0, 2, 0, 1, 2, 3, 1, 3, 2, 2, 3, 3};
  const int tq[16] = {0, 1, 0, 1, 2, 0, 3, 2, 1, 0, 3, 1, 2, 3, 2, 3};
  f32x4 acc = {};
  for (int t = toff[ij]; t < toff[ij + 1]; ++t) {
    gemm32_acc(Ph + (size_t)tp[t] * MSZ, Pl + (size_t)tp[t] * MSZ, i0,
               QTh + (size_t)tq[t] * MSZ, QTl + (size_t)tq[t] * MSZ, j0, 256, &acc, smem, tid);
  }
  #pragma unroll
  for (int v = 0; v < 4; ++v) {
    int r = i0 + orow + v, c = j0 + ocol;
    size_t idxT = (size_t)ij * MSZ + (size_t)c * 256 + r;  // R^T
    split_st(&RTh[idxT], &RTl[idxT], acc[v]);
  }
}

// ---------------- Wb[ij][cout][cin] = bf16((H·R[ij])^T) ----------------
__global__ __launch_bounds__(256) void final_k(
    const u16* __restrict__ Hh, const u16* __restrict__ Hl,
    const u16* __restrict__ RTh, const u16* __restrict__ RTl,
    u16* __restrict__ WBQ) {
  GEMM_IDX
  int ij = blockIdx.y;
  f32x4 acc = {};
  gemm32_acc(Hh, Hl, i0, RTh + (size_t)ij * MSZ, RTl + (size_t)ij * MSZ, j0,
             256, &acc, smem, tid);
  #pragma unroll
  for (int v = 0; v < 4; ++v) {
    int r = i0 + orow + v, c = j0 + ocol;
    WBQ[(size_t)ij * MSZ + (size_t)c * 256 + r] = f2bf(acc[v]);
  }
}

// ---------------- conv: implicit GEMM, MFMA bf16 ----------------
// grid 512 (XCD-swizzled): L = ht + 16*n; 512 threads (8 waves, 2M x 4N)
// block tile: 256 pos (4h x 64w) x 256 cout; wave tile 128 pos x 64 cout.
// K = cin(4 tiles of 64) x 9 taps; double-buffered W, 1 barrier/tap.
__global__ __launch_bounds__(512, 2) void conv_k(
    const u16* __restrict__ xb, const u16* __restrict__ Wb,
    const float* __restrict__ bias, float* __restrict__ out) {
  int braw = blockIdx.x;
  int L = (braw & 7) * 64 + (braw >> 3);   // bijective XCD swizzle (512 % 8 == 0)
  int ht = L & 15, n = L >> 4;
  int h0 = ht * 4;
  int tid = threadIdx.x;
  int lane = tid & 63, wave = tid >> 6;
  int wm = wave >> 2, wn = wave & 3;       // 2 M-halves x 4 N-quarters
  int fr = lane & 15, q = lane >> 4;

  __shared__ char smem[114688];            // 48KB sX + 2x32KB sW
  char* sX = smem;                         // [r6][w64][128B cin] swizzled
  char* sW = smem + 49152;                 // [buf2][cout256][128B cin] swizzled

  f32x4 acc[8][4] = {};
  uint4 xr[6], wr[4];

  auto loadX = [&](int ct) {
    #pragma unroll
    for (int p = 0; p < 6; ++p) {
      int e = tid + p * 512;
      int cb = (e & 7) * 16;
      int w = (e >> 3) & 63;
      int r = e >> 9;
      int hs = (h0 - 1 + r) & 63;
      xr[p] = *(const uint4*)((const char*)xb + (((size_t)(n * 64 + hs) * 64 + w) << 9) + ct * 128 + cb);
    }
  };
  auto storeX = [&]() {
    #pragma unroll
    for (int p = 0; p < 6; ++p) {
      int e = tid + p * 512;
      int cb = (e & 7) * 16;
      int w = (e >> 3) & 63;
      int r = e >> 9;
      *(uint4*)(sX + (r * 64 + w) * 128 + (cb ^ ((w & 7) << 4))) = xr[p];
    }
  };
  auto loadW = [&](int g2) {
    int ct2 = g2 / 9, tap2 = g2 - ct2 * 9;
    #pragma unroll
    for (int p = 0; p < 4; ++p) {
      int e = tid + p * 512;
      int cb = (e & 7) * 16;
      int cl = e >> 3;                     // cout 0..255
      wr[p] = *(const uint4*)((const char*)Wb + ((size_t)(tap2 * 256 + cl) << 9) + ct2 * 128 + cb);
    }
  };
  auto storeW = [&](int buf) {
    #pragma unroll
    for (int p = 0; p < 4; ++p) {
      int e = tid + p * 512;
      int cb = (e & 7) * 16;
      int cl = e >> 3;
      *(uint4*)(sW + buf * 32768 + cl * 128 + (cb ^ ((cl & 7) << 4))) = wr[p];
    }
  };

  loadX(0); loadW(0);
  storeX(); storeW(0);
  loadW(1);
  __syncthreads();

  for (int g = 0; g < 36; ++g) {
    int ct = g / 9, tap = g - ct * 9;
    int kh = tap % 3, kw = tap / 3;
    if (g + 1 < 36) storeW((g + 1) & 1);   // regs hold W[g+1]; buf was last read at g-1
    if (g + 2 < 36) loadW(g + 2);
    if (tap == 7 && ct < 3) loadX(ct + 1);
    // compute tap g from buf[g&1]
    #pragma unroll
    for (int ks = 0; ks < 2; ++ks) {
      int kb = ks * 64 + q * 16;
      bf16x8 af[8], bfr[4];
      #pragma unroll
      for (int fm = 0; fm < 8; ++fm) {
        int xrow = wm * 2 + (fm >> 2) + kh;
        int wsrc = ((fm & 3) * 16 + fr + kw + 63) & 63;
        af[fm] = *(const bf16x8*)(sX + (xrow * 64 + wsrc) * 128 + (kb ^ ((wsrc & 7) << 4)));
      }
      #pragma unroll
      for (int fn = 0; fn < 4; ++fn) {
        int cl = wn * 64 + fn * 16 + fr;
        bfr[fn] = *(const bf16x8*)(sW + (g & 1) * 32768 + cl * 128 + (kb ^ ((cl & 7) << 4)));
      }
      #pragma unroll
      for (int fm = 0; fm < 8; ++fm)
        #pragma unroll
        for (int fn = 0; fn < 4; ++fn)
          acc[fm][fn] = __builtin_amdgcn_mfma_f32_16x16x32_bf16(af[fm], bfr[fn], acc[fm][fn], 0, 0, 0);
    }
    if (tap == 8 && ct < 3) {
      __syncthreads();                     // all waves done reading sX (and buf)
      storeX();                            // X[ct+1] (regs loaded at tap 7)
      __syncthreads();                     // sX + sW[g+1] visible
    } else {
      __syncthreads();                     // end of tap: buf[g+1] stores visible
    }
  }

  // epilogue: 4 rounds of 64 cout x 4h x 64w f32 (64KB) through LDS
  float* sF = (float*)smem;
  int c_local = wn * 16 + fr;              // 0..63
  #pragma unroll
  for (int fn = 0; fn < 4; ++fn) {
    float bv = bias[wn * 64 + fn * 16 + fr];
    #pragma unroll
    for (int fm = 0; fm < 8; ++fm) {
      int h_local = wm * 2 + (fm >> 2);
      int slot = (fm & 3) * 4 + q;         // w-16B-slot 0..15
      f32x4 v = acc[fm][fn];
      v[0] += bv; v[1] += bv; v[2] += bv; v[3] += bv;
      *(f32x4*)((char*)sF + (c_local * 4 + h_local) * 256 + ((slot * 16) ^ ((c_local & 15) << 4))) = v;
    }
    __syncthreads();
    #pragma unroll
    for (int p = 0; p < 8; ++p) {
      int e = tid + p * 512;
      int w4 = e & 15, hh = (e >> 4) & 3, cl = e >> 6;   // cl 0..63
      int cg = (cl >> 4) * 64 + fn * 16 + (cl & 15);
      f32x4 val = *(const f32x4*)((const char*)sF + (cl * 4 + hh) * 256 + ((w4 * 16) ^ ((cl & 15) << 4)));
      *(f32x4*)(out + (((size_t)n * 256 + cg) * 64 + (h0 + hh)) * 64 + w4 * 4) = val;
    }
    if (fn < 3) __syncthreads();           // WAR before next round's LDS stores
  }
}

extern "C" void kernel_launch(void* const* d_in, const int* in_sizes, int n_in,
                              void* d_out, int out_size, void* d_ws, size_t ws_size,
                              hipStream_t stream) {
  const float* x = (const float*)d_in[0];
  const float* param = (const float*)d_in[1];
  const float* u0 = (const float*)d_in[2];
  const float* bias = (const float*)d_in[3];
  float* out = (float*)d_out;
  char* ws = (char*)d_ws;
  (void)in_sizes; (void)n_in; (void)out_size; (void)ws_size;

  float* At = (float*)(ws + O_AT);
  float* sval = (float*)(ws + O_SVAL);
  u16* W0h  = (u16*)(ws + O_W0);   u16* W0l  = W0h + 327680;
  u16* W0th = W0l + 327680;        u16* W0tl = W0th + 327680;
  u16* W1h  = (u16*)(ws + O_W1);   u16* W1l  = W1h + 327680;
  u16* W1th = W1l + 327680;        u16* W1tl = W1th + 327680;
  u16* Th = (u16*)(ws + O_TH);     u16* Tl = (u16*)(ws + O_TL);
  u16* PQh = (u16*)(ws + O_PQH);   u16* PQl = (u16*)(ws + O_PQL);
  u16* C1h = (u16*)(ws + O_C1H);   u16* C1l = (u16*)(ws + O_C1L);
  u16* C2h = (u16*)(ws + O_C2H);   u16* C2l = (u16*)(ws + O_C2L);
  u16* C2th = (u16*)(ws + O_C2TH); u16* C2tl = (u16*)(ws + O_C2TL);
  u16* Ph = (u16*)(ws + O_PH);     u16* Pl = (u16*)(ws + O_PL);
  u16* QTh = (u16*)(ws + O_QTH);   u16* QTl = (u16*)(ws + O_QTL);
  u16* RTh = (u16*)(ws + O_RTH);   u16* RTl = (u16*)(ws + O_RTL);
  u16* WBQ = (u16*)(ws + O_WBQ);

  convert_k<<<32768, 256, 0, stream>>>(x, (u16*)(ws + O_XB));
  transpose_k<<<dim3(64, 5), 256, 0, stream>>>(param, At);
  power_k<<<5, 256, 0, stream>>>(param, At, u0, sval);
  scale_k<<<1280, 256, 0, stream>>>(param, At, sval, W0h, W0l, W0th, W0tl);

  u16 *cWh = W0h, *cWl = W0l, *cWth = W0th, *cWtl = W0tl;
  u16 *nWh = W1h, *nWl = W1l, *nWth = W1th, *nWtl = W1tl;
  for (int it = 0; it < 20; ++it) {
    bjorck_t_k<<<dim3(64, 5), 256, 0, stream>>>(cWth, cWtl, Th, Tl);
    bjorck_u_k<<<dim3(64, 5), 256, 0, stream>>>(cWh, cWl, Th, Tl, nWh, nWl, nWth, nWtl);
    u16* t0;
    t0 = cWh; cWh = nWh; nWh = t0;
    t0 = cWl; cWl = nWl; nWl = t0;
    t0 = cWth; cWth = nWth; nWth = t0;
    t0 = cWtl; cWtl = nWtl; nWtl = t0;
  }
  // after 20 swaps cur == W0; W1 region is dead -> P/QT alias is safe

  pq_k<<<dim3(64, 4), 256, 0, stream>>>(cWh, cWl, PQh, PQl);
  c12_k<<<dim3(64, 3), 256, 0, stream>>>(PQh, PQl, C1h, C1l, C2h, C2l, C2th, C2tl);
  blocks_k<<<256, 256, 0, stream>>>(PQh, PQl, C1h, C1l, C2th, C2tl, Ph, Pl, QTh, QTl);
  mconv_k<<<dim3(64, 9), 256, 0, stream>>>(Ph, Pl, QTh, QTl, RTh, RTl);
  final_k<<<dim3(64, 9), 256, 0, stream>>>(cWh, cWl, RTh, RTl, WBQ);

  conv_k<<<512, 512, 0, stream>>>((const u16*)(ws + O_XB), WBQ, bias, out);
}